// Round 9
// baseline (370.576 us; speedup 1.0000x reference)
//
#include <hip/hip_runtime.h>
#include <hip/hip_bf16.h>

#define N_NODES    50000
#define DIM        128
#define NUM_GRAPHS 64
#define NUM_CLASSES 3
#define NPAD       50176   // 196*256
#define XPITCH     136     // LDS row pitch in ushorts (17 x 16B, odd -> conflict-free b128)

typedef unsigned short ushort_t;
typedef unsigned int   uint_t;
typedef __attribute__((ext_vector_type(8))) short short8;
typedef __attribute__((ext_vector_type(4))) float f32x4;

__device__ __forceinline__ ushort_t f2bf(float f) {
    union { float f; uint_t u; } v; v.f = f;
    uint_t r = v.u + 0x7fffu + ((v.u >> 16) & 1u);   // RNE
    return (ushort_t)(r >> 16);
}
__device__ __forceinline__ float bflo(uint_t u) {
    union { uint_t u; float f; } v; v.u = u << 16; return v.f;
}
__device__ __forceinline__ float bfhi(uint_t u) {
    union { uint_t u; float f; } v; v.u = u & 0xffff0000u; return v.f;
}

// raw gather: acc += sum over {n} u N(n) of Tb'[s]   (Tb' rows pre-scaled by dinv[s])
// caller multiplies the result by dinv[n].
__device__ __forceinline__ void gather_raw(
    int n, int lane, const int* __restrict__ rowptr,
    const int* __restrict__ csr_src, const uint_t* __restrict__ Tb,
    float2& acc)
{
    int p0 = rowptr[n], p1 = rowptr[n + 1];
    uint_t us = Tb[n * 64 + lane];      // self loop
    float2 a0 = make_float2(bflo(us), bfhi(us));
    float2 a1 = make_float2(0.f, 0.f);
    int p = p0;
    for (; p + 16 <= p1; p += 16) {
        int s[16]; uint_t u[16];
        #pragma unroll
        for (int q = 0; q < 16; ++q) s[q] = csr_src[p + q];
        #pragma unroll
        for (int q = 0; q < 16; ++q) u[q] = Tb[s[q] * 64 + lane];
        #pragma unroll
        for (int q = 0; q < 16; q += 2) {
            a0.x += bflo(u[q]);     a0.y += bfhi(u[q]);
            a1.x += bflo(u[q + 1]); a1.y += bfhi(u[q + 1]);
        }
    }
    for (; p + 8 <= p1; p += 8) {
        int s[8]; uint_t u[8];
        #pragma unroll
        for (int q = 0; q < 8; ++q) s[q] = csr_src[p + q];
        #pragma unroll
        for (int q = 0; q < 8; ++q) u[q] = Tb[s[q] * 64 + lane];
        #pragma unroll
        for (int q = 0; q < 8; q += 2) {
            a0.x += bflo(u[q]);     a0.y += bfhi(u[q]);
            a1.x += bflo(u[q + 1]); a1.y += bfhi(u[q + 1]);
        }
    }
    for (; p + 4 <= p1; p += 4) {
        int s[4]; uint_t u[4];
        #pragma unroll
        for (int q = 0; q < 4; ++q) s[q] = csr_src[p + q];
        #pragma unroll
        for (int q = 0; q < 4; ++q) u[q] = Tb[s[q] * 64 + lane];
        #pragma unroll
        for (int q = 0; q < 4; q += 2) {
            a0.x += bflo(u[q]);     a0.y += bfhi(u[q]);
            a1.x += bflo(u[q + 1]); a1.y += bfhi(u[q + 1]);
        }
    }
    for (; p < p1; ++p) {
        int s = csr_src[p];
        uint_t u = Tb[s * 64 + lane];
        a0.x += bflo(u); a0.y += bfhi(u);
    }
    acc.x += a0.x + a1.x;
    acc.y += a0.y + a1.y;
}

// ---------------- init ----------------
__global__ void k_init(int* degi, float* pooled, float* counts) {
    int i = blockIdx.x * 256 + threadIdx.x;
    if (i < NPAD) degi[i] = 0;
    if (i < NUM_GRAPHS * DIM) pooled[i] = 0.0f;
    if (i < NUM_GRAPHS) counts[i] = 0.0f;
}

// ---------------- W -> Wt bf16 transpose (all 3 layers) ----------------
__global__ void k_prep(const float* __restrict__ W1, const float* __restrict__ W2,
                       const float* __restrict__ W3, ushort_t* __restrict__ Wt) {
    int i = blockIdx.x * 256 + threadIdx.x;
    int mat = i >> 14;
    int idx = i & 16383;
    const float* W = (mat == 0) ? W1 : (mat == 1) ? W2 : W3;
    int n = idx >> 7, k = idx & 127;
    Wt[mat * 16384 + n * 128 + k] = f2bf(W[k * 128 + n]);
}

// ---------------- degree histogram; atomic return = within-row rank ----------------
__global__ void k_count(const int* __restrict__ dst, int* degi, int* rank, int nedges) {
    int e = blockIdx.x * 256 + threadIdx.x;
    if (e < nedges) rank[e] = atomicAdd(&degi[dst[e]], 1);
}

// ---------------- scan ----------------
__global__ __launch_bounds__(256) void k_scan1(const int* __restrict__ degi,
                                               int* rowptr, int* bsum) {
    __shared__ int sh[256];
    int i = blockIdx.x * 256 + threadIdx.x;
    int v = degi[i];
    sh[threadIdx.x] = v;
    __syncthreads();
    for (int off = 1; off < 256; off <<= 1) {
        int t = (threadIdx.x >= off) ? sh[threadIdx.x - off] : 0;
        __syncthreads();
        sh[threadIdx.x] += t;
        __syncthreads();
    }
    rowptr[i] = sh[threadIdx.x] - v;
    if (threadIdx.x == 255) bsum[blockIdx.x] = sh[255];
}

__global__ __launch_bounds__(256) void k_scan2(int* bsum, int nblocks) {
    __shared__ int sh[256];
    int v = (threadIdx.x < nblocks) ? bsum[threadIdx.x] : 0;
    sh[threadIdx.x] = v;
    __syncthreads();
    for (int off = 1; off < 256; off <<= 1) {
        int t = (threadIdx.x >= off) ? sh[threadIdx.x - off] : 0;
        __syncthreads();
        sh[threadIdx.x] += t;
        __syncthreads();
    }
    if (threadIdx.x < nblocks) bsum[threadIdx.x] = sh[threadIdx.x] - v;
}

__global__ __launch_bounds__(256) void k_scan3(int* rowptr, const int* __restrict__ bsum,
                                               const int* __restrict__ degi,
                                               float* dinv) {
    int i = blockIdx.x * 256 + threadIdx.x;
    rowptr[i] = rowptr[i] + bsum[blockIdx.x];
    if (i < N_NODES) dinv[i] = rsqrtf((float)degi[i] + 1.0f);
}

// ---------------- CSR fill: atomic-free scatter via precomputed rank ----------------
__global__ void k_fill(const int* __restrict__ src, const int* __restrict__ dst,
                       const int* __restrict__ rank, const int* __restrict__ rowptr,
                       int* csr_src, int nedges) {
    int e = blockIdx.x * 256 + threadIdx.x;
    if (e < nedges) csr_src[rowptr[dst[e]] + rank[e]] = src[e];
}

// ---------------- layer-1 matmul: Tb1' = (x @ W1) * dinv[row] ----------------
__global__ __launch_bounds__(256) void k_mm1(
    const float* __restrict__ xin, const ushort_t* __restrict__ WtG,
    const float* __restrict__ dinv, ushort_t* __restrict__ TbOut)
{
    __shared__ ushort_t Wl[DIM * XPITCH];
    __shared__ ushort_t Xl[64 * XPITCH];

    const int tid = threadIdx.x;
    const int rowbase = blockIdx.x * 64;

    #pragma unroll
    for (int i = 0; i < 8; ++i) {
        int g = tid + i * 256;
        uint4 v = ((const uint4*)WtG)[g];
        *((uint4*)&Wl[(g >> 4) * XPITCH + (g & 15) * 8]) = v;
    }
    #pragma unroll
    for (int i = 0; i < 8; ++i) {
        int c = tid + i * 256;
        int row = c >> 5;
        int grow = rowbase + row;
        float4 f = make_float4(0.f, 0.f, 0.f, 0.f);
        if (grow < N_NODES)
            f = ((const float4*)xin)[(long long)rowbase * 32 + c];
        ushort4 h;
        h.x = f2bf(f.x); h.y = f2bf(f.y); h.z = f2bf(f.z); h.w = f2bf(f.w);
        *((ushort4*)&Xl[row * XPITCH + (c & 31) * 4]) = h;
    }
    __syncthreads();

    const int wave = tid >> 6;
    const int lane = tid & 63;
    const int quad = lane >> 4;
    const int lm   = lane & 15;
    const int m0   = wave * 16;

    short8 af[4];
    #pragma unroll
    for (int k0 = 0; k0 < 4; ++k0)
        af[k0] = *(const short8*)&Xl[(m0 + lm) * XPITCH + k0 * 32 + quad * 8];

    int noder[4]; float di[4]; bool okr[4];
    #pragma unroll
    for (int r = 0; r < 4; ++r) {
        noder[r] = rowbase + m0 + quad * 4 + r;
        okr[r] = (noder[r] < N_NODES);
        di[r] = okr[r] ? dinv[noder[r]] : 0.f;
    }

    for (int n0 = 0; n0 < DIM; n0 += 16) {
        f32x4 acc = {0.f, 0.f, 0.f, 0.f};
        #pragma unroll
        for (int k0 = 0; k0 < 4; ++k0) {
            short8 bf = *(const short8*)&Wl[(n0 + lm) * XPITCH + k0 * 32 + quad * 8];
            acc = __builtin_amdgcn_mfma_f32_16x16x32_bf16(af[k0], bf, acc, 0, 0, 0);
        }
        int n = n0 + lm;
        #pragma unroll
        for (int r = 0; r < 4; ++r)
            if (okr[r])
                TbOut[(long long)noder[r] * DIM + n] = f2bf(acc[r] * di[r]);
    }
}

// ---------------- fused: X = ReLU(b + dinv[n]*Sum Tb'[s]) ; Tb_out' = (X@W)*dinv ----------------
__global__ __launch_bounds__(256) void k_fused(
    const int* __restrict__ rowptr, const int* __restrict__ csr_src,
    const float* __restrict__ dinv, const uint_t* __restrict__ TbIn,
    const ushort_t* __restrict__ WtG, const float* __restrict__ b_prev,
    ushort_t* __restrict__ TbOut)
{
    __shared__ ushort_t Xl[16 * XPITCH];   // 4352 B

    const int tid = threadIdx.x;
    const int rowbase = blockIdx.x * 16;
    const int wave = tid >> 6;
    const int lane = tid & 63;

    float2 bias2 = ((const float2*)b_prev)[lane];

    #pragma unroll
    for (int t = 0; t < 4; ++t) {
        int r = wave * 4 + t;
        int n = rowbase + r;
        float2 acc = make_float2(0.f, 0.f);
        float dd = 0.f;
        if (n < N_NODES) {
            dd = dinv[n];
            gather_raw(n, lane, rowptr, csr_src, TbIn, acc);
        }
        ushort2 h;
        h.x = f2bf(fmaxf(bias2.x + acc.x * dd, 0.f));
        h.y = f2bf(fmaxf(bias2.y + acc.y * dd, 0.f));
        *((ushort2*)&Xl[r * XPITCH + lane * 2]) = h;
    }
    __syncthreads();

    const int quad = lane >> 4;
    const int lm   = lane & 15;

    short8 af[4];
    #pragma unroll
    for (int k0 = 0; k0 < 4; ++k0)
        af[k0] = *(const short8*)&Xl[lm * XPITCH + k0 * 32 + quad * 8];

    int noder[4]; float di[4]; bool okr[4];
    #pragma unroll
    for (int r = 0; r < 4; ++r) {
        noder[r] = rowbase + quad * 4 + r;
        okr[r] = (noder[r] < N_NODES);
        di[r] = okr[r] ? dinv[noder[r]] : 0.f;
    }

    #pragma unroll
    for (int h = 0; h < 2; ++h) {
        int n0 = wave * 32 + h * 16;
        f32x4 acc = {0.f, 0.f, 0.f, 0.f};
        #pragma unroll
        for (int k0 = 0; k0 < 4; ++k0) {
            short8 bf = *(const short8*)&WtG[(n0 + lm) * DIM + k0 * 32 + quad * 8];
            acc = __builtin_amdgcn_mfma_f32_16x16x32_bf16(af[k0], bf, acc, 0, 0, 0);
        }
        int n = n0 + lm;
        #pragma unroll
        for (int r = 0; r < 4; ++r)
            if (okr[r])
                TbOut[(long long)noder[r] * DIM + n] = f2bf(acc[r] * di[r]);
    }
}

// ---------------- fused gather + mean-pool: wave per 4-row strip ----------------
__global__ __launch_bounds__(256) void k_poolgather(
    const int* __restrict__ rowptr, const int* __restrict__ csr_src,
    const float* __restrict__ dinv, const uint_t* __restrict__ Tb,
    const float* __restrict__ b3, const int* __restrict__ batch,
    float* pooled, float* counts)
{
    const int wave = threadIdx.x >> 6;
    const int lane = threadIdx.x & 63;
    int n0 = blockIdx.x * 16 + wave * 4;
    if (n0 >= N_NODES) return;
    int nend = min(n0 + 4, N_NODES);

    float2 bias2 = ((const float2*)b3)[lane];
    int cur = batch[n0];
    int runstart = n0;
    float2 pacc = make_float2(0.f, 0.f);

    for (int n = n0; n < nend; ++n) {
        int g = batch[n];
        if (g != cur) {
            atomicAdd(&pooled[cur * DIM + 2 * lane], pacc.x);
            atomicAdd(&pooled[cur * DIM + 2 * lane + 1], pacc.y);
            if (lane == 0) atomicAdd(&counts[cur], (float)(n - runstart));
            pacc.x = 0.f; pacc.y = 0.f; cur = g; runstart = n;
        }
        float2 acc = make_float2(0.f, 0.f);
        gather_raw(n, lane, rowptr, csr_src, Tb, acc);
        float dd = dinv[n];
        pacc.x += bias2.x + acc.x * dd;
        pacc.y += bias2.y + acc.y * dd;
    }
    atomicAdd(&pooled[cur * DIM + 2 * lane], pacc.x);
    atomicAdd(&pooled[cur * DIM + 2 * lane + 1], pacc.y);
    if (lane == 0) atomicAdd(&counts[cur], (float)(nend - runstart));
}

// ---------------- classifier head ----------------
__global__ __launch_bounds__(128) void k_cls(
    const float* __restrict__ pooled, const float* __restrict__ counts,
    const float* __restrict__ C1, const float* __restrict__ bc1,
    const float* __restrict__ C2, const float* __restrict__ bc2,
    float* out)
{
    __shared__ float pm[DIM];
    __shared__ float gv[DIM];
    int g = blockIdx.x, j = threadIdx.x;
    float cnt = fmaxf(counts[g], 1.0f);
    pm[j] = pooled[g * DIM + j] / cnt;
    __syncthreads();
    float a = bc1[j];
    for (int k = 0; k < DIM; ++k) a += pm[k] * C1[k * DIM + j];
    gv[j] = fmaxf(a, 0.f);
    __syncthreads();
    if (j < NUM_CLASSES) {
        float o = bc2[j];
        for (int k = 0; k < DIM; ++k) o += gv[k] * C2[k * NUM_CLASSES + j];
        out[g * NUM_CLASSES + j] = o;
    }
}

extern "C" void kernel_launch(void* const* d_in, const int* in_sizes, int n_in,
                              void* d_out, int out_size, void* d_ws, size_t ws_size,
                              hipStream_t stream) {
    const float* x    = (const float*)d_in[0];
    const int*   ei   = (const int*)d_in[1];
    const int*   batch= (const int*)d_in[2];
    const float* W1   = (const float*)d_in[3];
    const float* b1   = (const float*)d_in[4];
    const float* W2   = (const float*)d_in[5];
    const float* b2   = (const float*)d_in[6];
    const float* W3   = (const float*)d_in[7];
    const float* b3   = (const float*)d_in[8];
    const float* C1   = (const float*)d_in[9];
    const float* bc1  = (const float*)d_in[10];
    const float* C2   = (const float*)d_in[11];
    const float* bc2  = (const float*)d_in[12];

    const int nedges = in_sizes[1] / 2;
    const int* src = ei;
    const int* dst = ei + nedges;

    // workspace layout (4-byte units)
    float*    dinv    = (float*)d_ws;                           // NPAD
    uint_t*   TbA     = (uint_t*)(dinv + NPAD);                 // N_NODES*64
    uint_t*   TbB     = TbA + (long long)N_NODES * 64;          // N_NODES*64
    float*    pooled  = (float*)(TbB + (long long)N_NODES * 64);// 8192
    float*    counts  = pooled + NUM_GRAPHS * DIM;              // 64
    int*      degi    = (int*)(counts + 64);                    // NPAD
    int*      rowptr  = degi + NPAD;                            // NPAD+256
    int*      bsum    = rowptr + NPAD + 256;                    // 256
    int*      rank    = bsum + 256;                             // nedges
    int*      csr_src = rank + nedges;                          // nedges
    ushort_t* Wt      = (ushort_t*)(csr_src + nedges);          // 3*16384 bf16

    const int nodeBlocks = NPAD / 256;                     // 196
    const int mmBlocks   = (N_NODES + 63) / 64;            // 782
    const int fusedBlocks= (N_NODES + 15) / 16;            // 3125
    const int edgeBlocks = (nedges + 255) / 256;           // 3125

    k_init<<<nodeBlocks, 256, 0, stream>>>(degi, pooled, counts);
    k_prep<<<192, 256, 0, stream>>>(W1, W2, W3, Wt);
    k_count<<<edgeBlocks, 256, 0, stream>>>(dst, degi, rank, nedges);
    k_scan1<<<nodeBlocks, 256, 0, stream>>>(degi, rowptr, bsum);
    k_scan2<<<1, 256, 0, stream>>>(bsum, nodeBlocks);
    k_scan3<<<nodeBlocks, 256, 0, stream>>>(rowptr, bsum, degi, dinv);
    k_fill<<<edgeBlocks, 256, 0, stream>>>(src, dst, rank, rowptr, csr_src, nedges);

    k_mm1<<<mmBlocks, 256, 0, stream>>>(x, Wt, dinv, (ushort_t*)TbA);
    k_fused<<<fusedBlocks, 256, 0, stream>>>(rowptr, csr_src, dinv, TbA,
                                             Wt + 16384, b1, (ushort_t*)TbB);
    k_fused<<<fusedBlocks, 256, 0, stream>>>(rowptr, csr_src, dinv, TbB,
                                             Wt + 32768, b2, (ushort_t*)TbA);
    k_poolgather<<<fusedBlocks, 256, 0, stream>>>(rowptr, csr_src, dinv, TbA,
                                                  b3, batch, pooled, counts);
    k_cls<<<NUM_GRAPHS, 128, 0, stream>>>(pooled, counts, C1, bc1, C2, bc2,
                                          (float*)d_out);
}

// Round 10
// 327.753 us; speedup vs baseline: 1.1307x; 1.1307x over previous
//
#include <hip/hip_runtime.h>
#include <hip/hip_bf16.h>

#define N_NODES    50000
#define DIM        128
#define NUM_GRAPHS 64
#define NUM_CLASSES 3
#define NPAD       50176   // 196*256
#define XPITCH     136     // LDS row pitch in ushorts (17 x 16B, odd -> conflict-free b128)

typedef unsigned short ushort_t;
typedef unsigned int   uint_t;
typedef __attribute__((ext_vector_type(8))) short short8;
typedef __attribute__((ext_vector_type(4))) float f32x4;

__device__ __forceinline__ ushort_t f2bf(float f) {
    union { float f; uint_t u; } v; v.f = f;
    uint_t r = v.u + 0x7fffu + ((v.u >> 16) & 1u);   // RNE
    return (ushort_t)(r >> 16);
}
__device__ __forceinline__ float bflo(uint_t u) {
    union { uint_t u; float f; } v; v.u = u << 16; return v.f;
}
__device__ __forceinline__ float bfhi(uint_t u) {
    union { uint_t u; float f; } v; v.u = u & 0xffff0000u; return v.f;
}

// raw gather: acc += sum over {n} u N(n) of Tb'[s]   (Tb' rows pre-scaled by dinv[s])
// caller multiplies the result by dinv[n].
__device__ __forceinline__ void gather_raw(
    int n, int lane, const int* __restrict__ rowptr,
    const int* __restrict__ csr_src, const uint_t* __restrict__ Tb,
    float2& acc)
{
    int p0 = rowptr[n], p1 = rowptr[n + 1];
    uint_t us = Tb[n * 64 + lane];      // self loop
    float2 a0 = make_float2(bflo(us), bfhi(us));
    float2 a1 = make_float2(0.f, 0.f);
    int p = p0;
    for (; p + 16 <= p1; p += 16) {
        int s[16]; uint_t u[16];
        #pragma unroll
        for (int q = 0; q < 16; ++q) s[q] = csr_src[p + q];
        #pragma unroll
        for (int q = 0; q < 16; ++q) u[q] = Tb[s[q] * 64 + lane];
        #pragma unroll
        for (int q = 0; q < 16; q += 2) {
            a0.x += bflo(u[q]);     a0.y += bfhi(u[q]);
            a1.x += bflo(u[q + 1]); a1.y += bfhi(u[q + 1]);
        }
    }
    for (; p + 8 <= p1; p += 8) {
        int s[8]; uint_t u[8];
        #pragma unroll
        for (int q = 0; q < 8; ++q) s[q] = csr_src[p + q];
        #pragma unroll
        for (int q = 0; q < 8; ++q) u[q] = Tb[s[q] * 64 + lane];
        #pragma unroll
        for (int q = 0; q < 8; q += 2) {
            a0.x += bflo(u[q]);     a0.y += bfhi(u[q]);
            a1.x += bflo(u[q + 1]); a1.y += bfhi(u[q + 1]);
        }
    }
    for (; p + 4 <= p1; p += 4) {
        int s[4]; uint_t u[4];
        #pragma unroll
        for (int q = 0; q < 4; ++q) s[q] = csr_src[p + q];
        #pragma unroll
        for (int q = 0; q < 4; ++q) u[q] = Tb[s[q] * 64 + lane];
        #pragma unroll
        for (int q = 0; q < 4; q += 2) {
            a0.x += bflo(u[q]);     a0.y += bfhi(u[q]);
            a1.x += bflo(u[q + 1]); a1.y += bfhi(u[q + 1]);
        }
    }
    for (; p < p1; ++p) {
        int s = csr_src[p];
        uint_t u = Tb[s * 64 + lane];
        a0.x += bflo(u); a0.y += bfhi(u);
    }
    acc.x += a0.x + a1.x;
    acc.y += a0.y + a1.y;
}

// ---------------- init ----------------
__global__ void k_init(int* degi, float* pooled, float* counts) {
    int i = blockIdx.x * 256 + threadIdx.x;
    if (i < NPAD) degi[i] = 0;
    if (i < NUM_GRAPHS * DIM) pooled[i] = 0.0f;
    if (i < NUM_GRAPHS) counts[i] = 0.0f;
}

// ---------------- W -> Wt bf16 transpose (all 3 layers) ----------------
__global__ void k_prep(const float* __restrict__ W1, const float* __restrict__ W2,
                       const float* __restrict__ W3, ushort_t* __restrict__ Wt) {
    int i = blockIdx.x * 256 + threadIdx.x;
    int mat = i >> 14;
    int idx = i & 16383;
    const float* W = (mat == 0) ? W1 : (mat == 1) ? W2 : W3;
    int n = idx >> 7, k = idx & 127;
    Wt[mat * 16384 + n * 128 + k] = f2bf(W[k * 128 + n]);
}

// ---------------- degree histogram; atomic return = within-row rank ----------------
__global__ void k_count(const int* __restrict__ dst, int* degi, int* rank, int nedges) {
    int e = blockIdx.x * 256 + threadIdx.x;
    if (e < nedges) rank[e] = atomicAdd(&degi[dst[e]], 1);
}

// ---------------- scan ----------------
__global__ __launch_bounds__(256) void k_scan1(const int* __restrict__ degi,
                                               int* rowptr, int* bsum) {
    __shared__ int sh[256];
    int i = blockIdx.x * 256 + threadIdx.x;
    int v = degi[i];
    sh[threadIdx.x] = v;
    __syncthreads();
    for (int off = 1; off < 256; off <<= 1) {
        int t = (threadIdx.x >= off) ? sh[threadIdx.x - off] : 0;
        __syncthreads();
        sh[threadIdx.x] += t;
        __syncthreads();
    }
    rowptr[i] = sh[threadIdx.x] - v;
    if (threadIdx.x == 255) bsum[blockIdx.x] = sh[255];
}

__global__ __launch_bounds__(256) void k_scan2(int* bsum, int nblocks) {
    __shared__ int sh[256];
    int v = (threadIdx.x < nblocks) ? bsum[threadIdx.x] : 0;
    sh[threadIdx.x] = v;
    __syncthreads();
    for (int off = 1; off < 256; off <<= 1) {
        int t = (threadIdx.x >= off) ? sh[threadIdx.x - off] : 0;
        __syncthreads();
        sh[threadIdx.x] += t;
        __syncthreads();
    }
    if (threadIdx.x < nblocks) bsum[threadIdx.x] = sh[threadIdx.x] - v;
}

__global__ __launch_bounds__(256) void k_scan3(int* rowptr, const int* __restrict__ bsum,
                                               const int* __restrict__ degi,
                                               float* dinv) {
    int i = blockIdx.x * 256 + threadIdx.x;
    rowptr[i] = rowptr[i] + bsum[blockIdx.x];
    if (i < N_NODES) dinv[i] = rsqrtf((float)degi[i] + 1.0f);
}

// ---------------- CSR fill: atomic-free scatter via precomputed rank ----------------
__global__ void k_fill(const int* __restrict__ src, const int* __restrict__ dst,
                       const int* __restrict__ rank, const int* __restrict__ rowptr,
                       int* csr_src, int nedges) {
    int e = blockIdx.x * 256 + threadIdx.x;
    if (e < nedges) csr_src[rowptr[dst[e]] + rank[e]] = src[e];
}

// ---------------- layer-1 matmul: Tb1' = (x @ W1) * dinv[row] ----------------
__global__ __launch_bounds__(256) void k_mm1(
    const float* __restrict__ xin, const ushort_t* __restrict__ WtG,
    const float* __restrict__ dinv, ushort_t* __restrict__ TbOut)
{
    __shared__ ushort_t Wl[DIM * XPITCH];
    __shared__ ushort_t Xl[64 * XPITCH];

    const int tid = threadIdx.x;
    const int rowbase = blockIdx.x * 64;

    #pragma unroll
    for (int i = 0; i < 8; ++i) {
        int g = tid + i * 256;
        uint4 v = ((const uint4*)WtG)[g];
        *((uint4*)&Wl[(g >> 4) * XPITCH + (g & 15) * 8]) = v;
    }
    #pragma unroll
    for (int i = 0; i < 8; ++i) {
        int c = tid + i * 256;
        int row = c >> 5;
        int grow = rowbase + row;
        float4 f = make_float4(0.f, 0.f, 0.f, 0.f);
        if (grow < N_NODES)
            f = ((const float4*)xin)[(long long)rowbase * 32 + c];
        ushort4 h;
        h.x = f2bf(f.x); h.y = f2bf(f.y); h.z = f2bf(f.z); h.w = f2bf(f.w);
        *((ushort4*)&Xl[row * XPITCH + (c & 31) * 4]) = h;
    }
    __syncthreads();

    const int wave = tid >> 6;
    const int lane = tid & 63;
    const int quad = lane >> 4;
    const int lm   = lane & 15;
    const int m0   = wave * 16;

    short8 af[4];
    #pragma unroll
    for (int k0 = 0; k0 < 4; ++k0)
        af[k0] = *(const short8*)&Xl[(m0 + lm) * XPITCH + k0 * 32 + quad * 8];

    int noder[4]; float di[4]; bool okr[4];
    #pragma unroll
    for (int r = 0; r < 4; ++r) {
        noder[r] = rowbase + m0 + quad * 4 + r;
        okr[r] = (noder[r] < N_NODES);
        di[r] = okr[r] ? dinv[noder[r]] : 0.f;
    }

    for (int n0 = 0; n0 < DIM; n0 += 16) {
        f32x4 acc = {0.f, 0.f, 0.f, 0.f};
        #pragma unroll
        for (int k0 = 0; k0 < 4; ++k0) {
            short8 bf = *(const short8*)&Wl[(n0 + lm) * XPITCH + k0 * 32 + quad * 8];
            acc = __builtin_amdgcn_mfma_f32_16x16x32_bf16(af[k0], bf, acc, 0, 0, 0);
        }
        int n = n0 + lm;
        #pragma unroll
        for (int r = 0; r < 4; ++r)
            if (okr[r])
                TbOut[(long long)noder[r] * DIM + n] = f2bf(acc[r] * di[r]);
    }
}

// ---------------- fused: X = ReLU(b + dinv[n]*Sum Tb'[s]) ; Tb_out' = (X@W)*dinv ----------------
__global__ __launch_bounds__(256) void k_fused(
    const int* __restrict__ rowptr, const int* __restrict__ csr_src,
    const float* __restrict__ dinv, const uint_t* __restrict__ TbIn,
    const ushort_t* __restrict__ WtG, const float* __restrict__ b_prev,
    ushort_t* __restrict__ TbOut)
{
    __shared__ ushort_t Xl[16 * XPITCH];   // 4352 B

    const int tid = threadIdx.x;
    const int rowbase = blockIdx.x * 16;
    const int wave = tid >> 6;
    const int lane = tid & 63;

    float2 bias2 = ((const float2*)b_prev)[lane];

    #pragma unroll
    for (int t = 0; t < 4; ++t) {
        int r = wave * 4 + t;
        int n = rowbase + r;
        float2 acc = make_float2(0.f, 0.f);
        float dd = 0.f;
        if (n < N_NODES) {
            dd = dinv[n];
            gather_raw(n, lane, rowptr, csr_src, TbIn, acc);
        }
        ushort2 h;
        h.x = f2bf(fmaxf(bias2.x + acc.x * dd, 0.f));
        h.y = f2bf(fmaxf(bias2.y + acc.y * dd, 0.f));
        *((ushort2*)&Xl[r * XPITCH + lane * 2]) = h;
    }
    __syncthreads();

    const int quad = lane >> 4;
    const int lm   = lane & 15;

    short8 af[4];
    #pragma unroll
    for (int k0 = 0; k0 < 4; ++k0)
        af[k0] = *(const short8*)&Xl[lm * XPITCH + k0 * 32 + quad * 8];

    int noder[4]; float di[4]; bool okr[4];
    #pragma unroll
    for (int r = 0; r < 4; ++r) {
        noder[r] = rowbase + quad * 4 + r;
        okr[r] = (noder[r] < N_NODES);
        di[r] = okr[r] ? dinv[noder[r]] : 0.f;
    }

    #pragma unroll
    for (int h = 0; h < 2; ++h) {
        int n0 = wave * 32 + h * 16;
        f32x4 acc = {0.f, 0.f, 0.f, 0.f};
        #pragma unroll
        for (int k0 = 0; k0 < 4; ++k0) {
            short8 bf = *(const short8*)&WtG[(n0 + lm) * DIM + k0 * 32 + quad * 8];
            acc = __builtin_amdgcn_mfma_f32_16x16x32_bf16(af[k0], bf, acc, 0, 0, 0);
        }
        int n = n0 + lm;
        #pragma unroll
        for (int r = 0; r < 4; ++r)
            if (okr[r])
                TbOut[(long long)noder[r] * DIM + n] = f2bf(acc[r] * di[r]);
    }
}

// ---------------- fused gather + mean-pool: wave per 8-row strip (R8-proven shape) ----------------
__global__ __launch_bounds__(256) void k_poolgather(
    const int* __restrict__ rowptr, const int* __restrict__ csr_src,
    const float* __restrict__ dinv, const uint_t* __restrict__ Tb,
    const float* __restrict__ b3, const int* __restrict__ batch,
    float* pooled, float* counts)
{
    const int wave = threadIdx.x >> 6;
    const int lane = threadIdx.x & 63;
    int n0 = blockIdx.x * 32 + wave * 8;
    if (n0 >= N_NODES) return;
    int nend = min(n0 + 8, N_NODES);

    float2 bias2 = ((const float2*)b3)[lane];
    int cur = batch[n0];
    int runstart = n0;
    float2 pacc = make_float2(0.f, 0.f);

    for (int n = n0; n < nend; ++n) {
        int g = batch[n];
        if (g != cur) {
            atomicAdd(&pooled[cur * DIM + 2 * lane], pacc.x);
            atomicAdd(&pooled[cur * DIM + 2 * lane + 1], pacc.y);
            if (lane == 0) atomicAdd(&counts[cur], (float)(n - runstart));
            pacc.x = 0.f; pacc.y = 0.f; cur = g; runstart = n;
        }
        float2 acc = make_float2(0.f, 0.f);
        gather_raw(n, lane, rowptr, csr_src, Tb, acc);
        float dd = dinv[n];
        pacc.x += bias2.x + acc.x * dd;
        pacc.y += bias2.y + acc.y * dd;
    }
    atomicAdd(&pooled[cur * DIM + 2 * lane], pacc.x);
    atomicAdd(&pooled[cur * DIM + 2 * lane + 1], pacc.y);
    if (lane == 0) atomicAdd(&counts[cur], (float)(nend - runstart));
}

// ---------------- classifier head ----------------
__global__ __launch_bounds__(128) void k_cls(
    const float* __restrict__ pooled, const float* __restrict__ counts,
    const float* __restrict__ C1, const float* __restrict__ bc1,
    const float* __restrict__ C2, const float* __restrict__ bc2,
    float* out)
{
    __shared__ float pm[DIM];
    __shared__ float gv[DIM];
    int g = blockIdx.x, j = threadIdx.x;
    float cnt = fmaxf(counts[g], 1.0f);
    pm[j] = pooled[g * DIM + j] / cnt;
    __syncthreads();
    float a = bc1[j];
    for (int k = 0; k < DIM; ++k) a += pm[k] * C1[k * DIM + j];
    gv[j] = fmaxf(a, 0.f);
    __syncthreads();
    if (j < NUM_CLASSES) {
        float o = bc2[j];
        for (int k = 0; k < DIM; ++k) o += gv[k] * C2[k * NUM_CLASSES + j];
        out[g * NUM_CLASSES + j] = o;
    }
}

extern "C" void kernel_launch(void* const* d_in, const int* in_sizes, int n_in,
                              void* d_out, int out_size, void* d_ws, size_t ws_size,
                              hipStream_t stream) {
    const float* x    = (const float*)d_in[0];
    const int*   ei   = (const int*)d_in[1];
    const int*   batch= (const int*)d_in[2];
    const float* W1   = (const float*)d_in[3];
    const float* b1   = (const float*)d_in[4];
    const float* W2   = (const float*)d_in[5];
    const float* b2   = (const float*)d_in[6];
    const float* W3   = (const float*)d_in[7];
    const float* b3   = (const float*)d_in[8];
    const float* C1   = (const float*)d_in[9];
    const float* bc1  = (const float*)d_in[10];
    const float* C2   = (const float*)d_in[11];
    const float* bc2  = (const float*)d_in[12];

    const int nedges = in_sizes[1] / 2;
    const int* src = ei;
    const int* dst = ei + nedges;

    // workspace layout (4-byte units)
    float*    dinv    = (float*)d_ws;                           // NPAD
    uint_t*   TbA     = (uint_t*)(dinv + NPAD);                 // N_NODES*64
    uint_t*   TbB     = TbA + (long long)N_NODES * 64;          // N_NODES*64
    float*    pooled  = (float*)(TbB + (long long)N_NODES * 64);// 8192
    float*    counts  = pooled + NUM_GRAPHS * DIM;              // 64
    int*      degi    = (int*)(counts + 64);                    // NPAD
    int*      rowptr  = degi + NPAD;                            // NPAD+256
    int*      bsum    = rowptr + NPAD + 256;                    // 256
    int*      rank    = bsum + 256;                             // nedges
    int*      csr_src = rank + nedges;                          // nedges
    ushort_t* Wt      = (ushort_t*)(csr_src + nedges);          // 3*16384 bf16

    const int nodeBlocks = NPAD / 256;                     // 196
    const int mmBlocks   = (N_NODES + 63) / 64;            // 782
    const int fusedBlocks= (N_NODES + 15) / 16;            // 3125
    const int pgBlocks   = (N_NODES + 31) / 32;            // 1563
    const int edgeBlocks = (nedges + 255) / 256;           // 3125

    k_init<<<nodeBlocks, 256, 0, stream>>>(degi, pooled, counts);
    k_prep<<<192, 256, 0, stream>>>(W1, W2, W3, Wt);
    k_count<<<edgeBlocks, 256, 0, stream>>>(dst, degi, rank, nedges);
    k_scan1<<<nodeBlocks, 256, 0, stream>>>(degi, rowptr, bsum);
    k_scan2<<<1, 256, 0, stream>>>(bsum, nodeBlocks);
    k_scan3<<<nodeBlocks, 256, 0, stream>>>(rowptr, bsum, degi, dinv);
    k_fill<<<edgeBlocks, 256, 0, stream>>>(src, dst, rank, rowptr, csr_src, nedges);

    k_mm1<<<mmBlocks, 256, 0, stream>>>(x, Wt, dinv, (ushort_t*)TbA);
    k_fused<<<fusedBlocks, 256, 0, stream>>>(rowptr, csr_src, dinv, TbA,
                                             Wt + 16384, b1, (ushort_t*)TbB);
    k_fused<<<fusedBlocks, 256, 0, stream>>>(rowptr, csr_src, dinv, TbB,
                                             Wt + 32768, b2, (ushort_t*)TbA);
    k_poolgather<<<pgBlocks, 256, 0, stream>>>(rowptr, csr_src, dinv, TbA,
                                               b3, batch, pooled, counts);
    k_cls<<<NUM_GRAPHS, 128, 0, stream>>>(pooled, counts, C1, bc1, C2, bc2,
                                          (float*)d_out);
}

// Round 11
// 300.342 us; speedup vs baseline: 1.2338x; 1.0913x over previous
//
#include <hip/hip_runtime.h>
#include <hip/hip_bf16.h>

#define N_NODES    50000
#define DIM        128
#define NUM_GRAPHS 64
#define NUM_CLASSES 3
#define NPAD       50176   // 196*256
#define XPITCH     136     // LDS row pitch in ushorts (17 x 16B, odd -> conflict-free b128)

typedef unsigned short ushort_t;
typedef unsigned int   uint_t;
typedef __attribute__((ext_vector_type(8))) short short8;
typedef __attribute__((ext_vector_type(4))) float f32x4;

__device__ __forceinline__ ushort_t f2bf(float f) {
    union { float f; uint_t u; } v; v.f = f;
    uint_t r = v.u + 0x7fffu + ((v.u >> 16) & 1u);   // RNE
    return (ushort_t)(r >> 16);
}
__device__ __forceinline__ float bflo(uint_t u) {
    union { uint_t u; float f; } v; v.u = u << 16; return v.f;
}
__device__ __forceinline__ float bfhi(uint_t u) {
    union { uint_t u; float f; } v; v.u = u & 0xffff0000u; return v.f;
}

// raw gather, software-pipelined: acc += sum over {n} u N(n) of Tb'[s]
// (Tb' rows pre-scaled by dinv[s]; caller multiplies by dinv[n].)
// Double-buffered 8-batches: batch b+1's loads issue before batch b is consumed,
// so the accumulate waits on vmcnt(8) while 8 newer loads stay in flight.
__device__ __forceinline__ void gather_raw(
    int n, int lane, const int* __restrict__ rowptr,
    const int* __restrict__ csr_src, const uint_t* __restrict__ Tb,
    float2& acc)
{
    int p0 = rowptr[n], p1 = rowptr[n + 1];
    uint_t us = Tb[n * 64 + lane];      // self loop
    float2 a0 = make_float2(bflo(us), bfhi(us));
    float2 a1 = make_float2(0.f, 0.f);
    int p = p0;
    int nb = (p1 - p0) >> 3;            // full 8-batches
    if (nb > 0) {
        uint_t ucur[8];
        #pragma unroll
        for (int q = 0; q < 8; ++q) ucur[q] = Tb[csr_src[p + q] * 64 + lane];
        for (int b = 1; b < nb; ++b) {
            uint_t unxt[8];
            #pragma unroll
            for (int q = 0; q < 8; ++q) unxt[q] = Tb[csr_src[p + 8 + q] * 64 + lane];
            #pragma unroll
            for (int q = 0; q < 8; q += 2) {
                a0.x += bflo(ucur[q]);     a0.y += bfhi(ucur[q]);
                a1.x += bflo(ucur[q + 1]); a1.y += bfhi(ucur[q + 1]);
            }
            #pragma unroll
            for (int q = 0; q < 8; ++q) ucur[q] = unxt[q];
            p += 8;
        }
        #pragma unroll
        for (int q = 0; q < 8; q += 2) {
            a0.x += bflo(ucur[q]);     a0.y += bfhi(ucur[q]);
            a1.x += bflo(ucur[q + 1]); a1.y += bfhi(ucur[q + 1]);
        }
        p += 8;
    }
    for (; p + 4 <= p1; p += 4) {
        int s[4]; uint_t u[4];
        #pragma unroll
        for (int q = 0; q < 4; ++q) s[q] = csr_src[p + q];
        #pragma unroll
        for (int q = 0; q < 4; ++q) u[q] = Tb[s[q] * 64 + lane];
        #pragma unroll
        for (int q = 0; q < 4; q += 2) {
            a0.x += bflo(u[q]);     a0.y += bfhi(u[q]);
            a1.x += bflo(u[q + 1]); a1.y += bfhi(u[q + 1]);
        }
    }
    for (; p < p1; ++p) {
        int s = csr_src[p];
        uint_t u = Tb[s * 64 + lane];
        a0.x += bflo(u); a0.y += bfhi(u);
    }
    acc.x += a0.x + a1.x;
    acc.y += a0.y + a1.y;
}

// ---------------- init ----------------
__global__ void k_init(int* degi, float* pooled, float* counts) {
    int i = blockIdx.x * 256 + threadIdx.x;
    if (i < NPAD) degi[i] = 0;
    if (i < NUM_GRAPHS * DIM) pooled[i] = 0.0f;
    if (i < NUM_GRAPHS) counts[i] = 0.0f;
}

// ---------------- W -> Wt bf16 transpose (all 3 layers) ----------------
__global__ void k_prep(const float* __restrict__ W1, const float* __restrict__ W2,
                       const float* __restrict__ W3, ushort_t* __restrict__ Wt) {
    int i = blockIdx.x * 256 + threadIdx.x;
    int mat = i >> 14;
    int idx = i & 16383;
    const float* W = (mat == 0) ? W1 : (mat == 1) ? W2 : W3;
    int n = idx >> 7, k = idx & 127;
    Wt[mat * 16384 + n * 128 + k] = f2bf(W[k * 128 + n]);
}

// ---------------- degree histogram; atomic return = within-row rank ----------------
__global__ void k_count(const int* __restrict__ dst, int* degi, int* rank, int nedges) {
    int e = blockIdx.x * 256 + threadIdx.x;
    if (e < nedges) rank[e] = atomicAdd(&degi[dst[e]], 1);
}

// ---------------- scan ----------------
__global__ __launch_bounds__(256) void k_scan1(const int* __restrict__ degi,
                                               int* rowptr, int* bsum) {
    __shared__ int sh[256];
    int i = blockIdx.x * 256 + threadIdx.x;
    int v = degi[i];
    sh[threadIdx.x] = v;
    __syncthreads();
    for (int off = 1; off < 256; off <<= 1) {
        int t = (threadIdx.x >= off) ? sh[threadIdx.x - off] : 0;
        __syncthreads();
        sh[threadIdx.x] += t;
        __syncthreads();
    }
    rowptr[i] = sh[threadIdx.x] - v;
    if (threadIdx.x == 255) bsum[blockIdx.x] = sh[255];
}

__global__ __launch_bounds__(256) void k_scan2(int* bsum, int nblocks) {
    __shared__ int sh[256];
    int v = (threadIdx.x < nblocks) ? bsum[threadIdx.x] : 0;
    sh[threadIdx.x] = v;
    __syncthreads();
    for (int off = 1; off < 256; off <<= 1) {
        int t = (threadIdx.x >= off) ? sh[threadIdx.x - off] : 0;
        __syncthreads();
        sh[threadIdx.x] += t;
        __syncthreads();
    }
    if (threadIdx.x < nblocks) bsum[threadIdx.x] = sh[threadIdx.x] - v;
}

__global__ __launch_bounds__(256) void k_scan3(int* rowptr, const int* __restrict__ bsum,
                                               const int* __restrict__ degi,
                                               float* dinv) {
    int i = blockIdx.x * 256 + threadIdx.x;
    rowptr[i] = rowptr[i] + bsum[blockIdx.x];
    if (i < N_NODES) dinv[i] = rsqrtf((float)degi[i] + 1.0f);
}

// ---------------- CSR fill: atomic-free scatter via precomputed rank ----------------
__global__ void k_fill(const int* __restrict__ src, const int* __restrict__ dst,
                       const int* __restrict__ rank, const int* __restrict__ rowptr,
                       int* csr_src, int nedges) {
    int e = blockIdx.x * 256 + threadIdx.x;
    if (e < nedges) csr_src[rowptr[dst[e]] + rank[e]] = src[e];
}

// ---------------- layer-1 matmul: Tb1' = (x @ W1) * dinv[row] ----------------
__global__ __launch_bounds__(256) void k_mm1(
    const float* __restrict__ xin, const ushort_t* __restrict__ WtG,
    const float* __restrict__ dinv, ushort_t* __restrict__ TbOut)
{
    __shared__ ushort_t Wl[DIM * XPITCH];
    __shared__ ushort_t Xl[64 * XPITCH];

    const int tid = threadIdx.x;
    const int rowbase = blockIdx.x * 64;

    #pragma unroll
    for (int i = 0; i < 8; ++i) {
        int g = tid + i * 256;
        uint4 v = ((const uint4*)WtG)[g];
        *((uint4*)&Wl[(g >> 4) * XPITCH + (g & 15) * 8]) = v;
    }
    #pragma unroll
    for (int i = 0; i < 8; ++i) {
        int c = tid + i * 256;
        int row = c >> 5;
        int grow = rowbase + row;
        float4 f = make_float4(0.f, 0.f, 0.f, 0.f);
        if (grow < N_NODES)
            f = ((const float4*)xin)[(long long)rowbase * 32 + c];
        ushort4 h;
        h.x = f2bf(f.x); h.y = f2bf(f.y); h.z = f2bf(f.z); h.w = f2bf(f.w);
        *((ushort4*)&Xl[row * XPITCH + (c & 31) * 4]) = h;
    }
    __syncthreads();

    const int wave = tid >> 6;
    const int lane = tid & 63;
    const int quad = lane >> 4;
    const int lm   = lane & 15;
    const int m0   = wave * 16;

    short8 af[4];
    #pragma unroll
    for (int k0 = 0; k0 < 4; ++k0)
        af[k0] = *(const short8*)&Xl[(m0 + lm) * XPITCH + k0 * 32 + quad * 8];

    int noder[4]; float di[4]; bool okr[4];
    #pragma unroll
    for (int r = 0; r < 4; ++r) {
        noder[r] = rowbase + m0 + quad * 4 + r;
        okr[r] = (noder[r] < N_NODES);
        di[r] = okr[r] ? dinv[noder[r]] : 0.f;
    }

    for (int n0 = 0; n0 < DIM; n0 += 16) {
        f32x4 acc = {0.f, 0.f, 0.f, 0.f};
        #pragma unroll
        for (int k0 = 0; k0 < 4; ++k0) {
            short8 bf = *(const short8*)&Wl[(n0 + lm) * XPITCH + k0 * 32 + quad * 8];
            acc = __builtin_amdgcn_mfma_f32_16x16x32_bf16(af[k0], bf, acc, 0, 0, 0);
        }
        int n = n0 + lm;
        #pragma unroll
        for (int r = 0; r < 4; ++r)
            if (okr[r])
                TbOut[(long long)noder[r] * DIM + n] = f2bf(acc[r] * di[r]);
    }
}

// ---------------- fused: X = ReLU(b + dinv[n]*Sum Tb'[s]) ; Tb_out' = (X@W)*dinv ----------------
__global__ __launch_bounds__(256) void k_fused(
    const int* __restrict__ rowptr, const int* __restrict__ csr_src,
    const float* __restrict__ dinv, const uint_t* __restrict__ TbIn,
    const ushort_t* __restrict__ WtG, const float* __restrict__ b_prev,
    ushort_t* __restrict__ TbOut)
{
    __shared__ ushort_t Xl[16 * XPITCH];   // 4352 B

    const int tid = threadIdx.x;
    const int rowbase = blockIdx.x * 16;
    const int wave = tid >> 6;
    const int lane = tid & 63;

    float2 bias2 = ((const float2*)b_prev)[lane];

    #pragma unroll
    for (int t = 0; t < 4; ++t) {
        int r = wave * 4 + t;
        int n = rowbase + r;
        float2 acc = make_float2(0.f, 0.f);
        float dd = 0.f;
        if (n < N_NODES) {
            dd = dinv[n];
            gather_raw(n, lane, rowptr, csr_src, TbIn, acc);
        }
        ushort2 h;
        h.x = f2bf(fmaxf(bias2.x + acc.x * dd, 0.f));
        h.y = f2bf(fmaxf(bias2.y + acc.y * dd, 0.f));
        *((ushort2*)&Xl[r * XPITCH + lane * 2]) = h;
    }
    __syncthreads();

    const int quad = lane >> 4;
    const int lm   = lane & 15;

    short8 af[4];
    #pragma unroll
    for (int k0 = 0; k0 < 4; ++k0)
        af[k0] = *(const short8*)&Xl[lm * XPITCH + k0 * 32 + quad * 8];

    int noder[4]; float di[4]; bool okr[4];
    #pragma unroll
    for (int r = 0; r < 4; ++r) {
        noder[r] = rowbase + quad * 4 + r;
        okr[r] = (noder[r] < N_NODES);
        di[r] = okr[r] ? dinv[noder[r]] : 0.f;
    }

    #pragma unroll
    for (int h = 0; h < 2; ++h) {
        int n0 = wave * 32 + h * 16;
        f32x4 acc = {0.f, 0.f, 0.f, 0.f};
        #pragma unroll
        for (int k0 = 0; k0 < 4; ++k0) {
            short8 bf = *(const short8*)&WtG[(n0 + lm) * DIM + k0 * 32 + quad * 8];
            acc = __builtin_amdgcn_mfma_f32_16x16x32_bf16(af[k0], bf, acc, 0, 0, 0);
        }
        int n = n0 + lm;
        #pragma unroll
        for (int r = 0; r < 4; ++r)
            if (okr[r])
                TbOut[(long long)noder[r] * DIM + n] = f2bf(acc[r] * di[r]);
    }
}

// ---------------- fused gather + mean-pool, LDS flush accumulation ----------------
// 8-row strips (proven shape). Run flushes go to LDS slots (graph - gbase < 8);
// one global flush per block-graph at the end: ~210K global atomics vs 857K.
__global__ __launch_bounds__(256) void k_poolgather(
    const int* __restrict__ rowptr, const int* __restrict__ csr_src,
    const float* __restrict__ dinv, const uint_t* __restrict__ Tb,
    const float* __restrict__ b3, const int* __restrict__ batch,
    float* pooled, float* counts)
{
    __shared__ float lp[8][DIM];   // 4 KB
    __shared__ float lc[8];

    const int tid  = threadIdx.x;
    const int wave = tid >> 6;
    const int lane = tid & 63;
    const int blk0 = blockIdx.x * 32;

    #pragma unroll
    for (int i = 0; i < 4; ++i) ((float*)lp)[tid + i * 256] = 0.f;
    if (tid < 8) lc[tid] = 0.f;
    __syncthreads();

    const int gbase = batch[min(blk0, N_NODES - 1)];
    int n0 = blk0 + wave * 8;

    if (n0 < N_NODES) {
        int nend = min(n0 + 8, N_NODES);
        float2 bias2 = ((const float2*)b3)[lane];
        int cur = batch[n0];
        int runstart = n0;
        float2 pacc = make_float2(0.f, 0.f);

        for (int n = n0; n < nend; ++n) {
            int g = batch[n];
            if (g != cur) {
                int slot = cur - gbase;
                if (slot < 8) {
                    atomicAdd(&lp[slot][2 * lane], pacc.x);
                    atomicAdd(&lp[slot][2 * lane + 1], pacc.y);
                    if (lane == 0) atomicAdd(&lc[slot], (float)(n - runstart));
                } else {
                    atomicAdd(&pooled[cur * DIM + 2 * lane], pacc.x);
                    atomicAdd(&pooled[cur * DIM + 2 * lane + 1], pacc.y);
                    if (lane == 0) atomicAdd(&counts[cur], (float)(n - runstart));
                }
                pacc.x = 0.f; pacc.y = 0.f; cur = g; runstart = n;
            }
            float2 acc = make_float2(0.f, 0.f);
            gather_raw(n, lane, rowptr, csr_src, Tb, acc);
            float dd = dinv[n];
            pacc.x += bias2.x + acc.x * dd;
            pacc.y += bias2.y + acc.y * dd;
        }
        int slot = cur - gbase;
        if (slot < 8) {
            atomicAdd(&lp[slot][2 * lane], pacc.x);
            atomicAdd(&lp[slot][2 * lane + 1], pacc.y);
            if (lane == 0) atomicAdd(&lc[slot], (float)(nend - runstart));
        } else {
            atomicAdd(&pooled[cur * DIM + 2 * lane], pacc.x);
            atomicAdd(&pooled[cur * DIM + 2 * lane + 1], pacc.y);
            if (lane == 0) atomicAdd(&counts[cur], (float)(nend - runstart));
        }
    }
    __syncthreads();

    #pragma unroll
    for (int s = 0; s < 8; ++s) {
        if (lc[s] != 0.f) {
            if (tid < DIM) atomicAdd(&pooled[(gbase + s) * DIM + tid], lp[s][tid]);
            if (tid == DIM) atomicAdd(&counts[gbase + s], lc[s]);
        }
    }
}

// ---------------- classifier head ----------------
__global__ __launch_bounds__(128) void k_cls(
    const float* __restrict__ pooled, const float* __restrict__ counts,
    const float* __restrict__ C1, const float* __restrict__ bc1,
    const float* __restrict__ C2, const float* __restrict__ bc2,
    float* out)
{
    __shared__ float pm[DIM];
    __shared__ float gv[DIM];
    int g = blockIdx.x, j = threadIdx.x;
    float cnt = fmaxf(counts[g], 1.0f);
    pm[j] = pooled[g * DIM + j] / cnt;
    __syncthreads();
    float a = bc1[j];
    for (int k = 0; k < DIM; ++k) a += pm[k] * C1[k * DIM + j];
    gv[j] = fmaxf(a, 0.f);
    __syncthreads();
    if (j < NUM_CLASSES) {
        float o = bc2[j];
        for (int k = 0; k < DIM; ++k) o += gv[k] * C2[k * NUM_CLASSES + j];
        out[g * NUM_CLASSES + j] = o;
    }
}

extern "C" void kernel_launch(void* const* d_in, const int* in_sizes, int n_in,
                              void* d_out, int out_size, void* d_ws, size_t ws_size,
                              hipStream_t stream) {
    const float* x    = (const float*)d_in[0];
    const int*   ei   = (const int*)d_in[1];
    const int*   batch= (const int*)d_in[2];
    const float* W1   = (const float*)d_in[3];
    const float* b1   = (const float*)d_in[4];
    const float* W2   = (const float*)d_in[5];
    const float* b2   = (const float*)d_in[6];
    const float* W3   = (const float*)d_in[7];
    const float* b3   = (const float*)d_in[8];
    const float* C1   = (const float*)d_in[9];
    const float* bc1  = (const float*)d_in[10];
    const float* C2   = (const float*)d_in[11];
    const float* bc2  = (const float*)d_in[12];

    const int nedges = in_sizes[1] / 2;
    const int* src = ei;
    const int* dst = ei + nedges;

    // workspace layout (4-byte units)
    float*    dinv    = (float*)d_ws;                           // NPAD
    uint_t*   TbA     = (uint_t*)(dinv + NPAD);                 // N_NODES*64
    uint_t*   TbB     = TbA + (long long)N_NODES * 64;          // N_NODES*64
    float*    pooled  = (float*)(TbB + (long long)N_NODES * 64);// 8192
    float*    counts  = pooled + NUM_GRAPHS * DIM;              // 64
    int*      degi    = (int*)(counts + 64);                    // NPAD
    int*      rowptr  = degi + NPAD;                            // NPAD+256
    int*      bsum    = rowptr + NPAD + 256;                    // 256
    int*      rank    = bsum + 256;                             // nedges
    int*      csr_src = rank + nedges;                          // nedges
    ushort_t* Wt      = (ushort_t*)(csr_src + nedges);          // 3*16384 bf16

    const int nodeBlocks = NPAD / 256;                     // 196
    const int mmBlocks   = (N_NODES + 63) / 64;            // 782
    const int fusedBlocks= (N_NODES + 15) / 16;            // 3125
    const int pgBlocks   = (N_NODES + 31) / 32;            // 1563
    const int edgeBlocks = (nedges + 255) / 256;           // 3125

    k_init<<<nodeBlocks, 256, 0, stream>>>(degi, pooled, counts);
    k_prep<<<192, 256, 0, stream>>>(W1, W2, W3, Wt);
    k_count<<<edgeBlocks, 256, 0, stream>>>(dst, degi, rank, nedges);
    k_scan1<<<nodeBlocks, 256, 0, stream>>>(degi, rowptr, bsum);
    k_scan2<<<1, 256, 0, stream>>>(bsum, nodeBlocks);
    k_scan3<<<nodeBlocks, 256, 0, stream>>>(rowptr, bsum, degi, dinv);
    k_fill<<<edgeBlocks, 256, 0, stream>>>(src, dst, rank, rowptr, csr_src, nedges);

    k_mm1<<<mmBlocks, 256, 0, stream>>>(x, Wt, dinv, (ushort_t*)TbA);
    k_fused<<<fusedBlocks, 256, 0, stream>>>(rowptr, csr_src, dinv, TbA,
                                             Wt + 16384, b1, (ushort_t*)TbB);
    k_fused<<<fusedBlocks, 256, 0, stream>>>(rowptr, csr_src, dinv, TbB,
                                             Wt + 32768, b2, (ushort_t*)TbA);
    k_poolgather<<<pgBlocks, 256, 0, stream>>>(rowptr, csr_src, dinv, TbA,
                                               b3, batch, pooled, counts);
    k_cls<<<NUM_GRAPHS, 128, 0, stream>>>(pooled, counts, C1, bc1, C2, bc2,
                                          (float*)d_out);
}